// Round 1
// baseline (1177.210 us; speedup 1.0000x reference)
//
#include <hip/hip_runtime.h>

#define HH 256
#define WW 256
#define HWSZ (HH * WW)

// One thread handles 4 points: 3x float4 point loads + 1x float4 density load,
// fully coalesced. Atomic only when density > 0.5 (val==0 otherwise; adding 0
// is a no-op on a zero-initialized buffer, so skipping is exact).
__global__ __launch_bounds__(256) void scatter_k(
    const float* __restrict__ pts, const float* __restrict__ dens,
    float* __restrict__ flat, int N)
{
    int b = blockIdx.y;
    int t = blockIdx.x * 256 + threadIdx.x;
    int base = t * 4;
    if (base >= N) return;

    const float* pb = pts + (size_t)b * N * 3;
    const float* db = dens + (size_t)b * N;
    float* out = flat + (size_t)b * HWSZ;

    float xs[4], ys[4], zs[4], ds[4];
    int cnt;
    if (base + 4 <= N) {
        const float4* p4 = (const float4*)pb;
        const float4* d4 = (const float4*)db;
        float4 a = p4[3 * t];
        float4 bb = p4[3 * t + 1];
        float4 c = p4[3 * t + 2];
        float4 dd = d4[t];
        xs[0] = a.x;  ys[0] = a.y;  zs[0] = a.z;
        xs[1] = a.w;  ys[1] = bb.x; zs[1] = bb.y;
        xs[2] = bb.z; ys[2] = bb.w; zs[2] = c.x;
        xs[3] = c.y;  ys[3] = c.z;  zs[3] = c.w;
        ds[0] = dd.x; ds[1] = dd.y; ds[2] = dd.z; ds[3] = dd.w;
        cnt = 4;
    } else {
        cnt = N - base;
        for (int k = 0; k < cnt; k++) {
            xs[k] = pb[3 * (base + k) + 0];
            ys[k] = pb[3 * (base + k) + 1];
            zs[k] = pb[3 * (base + k) + 2];
            ds[k] = db[base + k];
        }
    }

    #pragma unroll
    for (int k = 0; k < 4; k++) {
        if (k < cnt) {
            float d = ds[k];
            if (d > 0.5f) {
                float z = zs[k];
                // ref: clip(int32((x/z + 0.5) * 256), 0, 255)
                // trunc-toward-zero then clip == clamp-in-float then trunc
                // (holds for negatives, overflow->inf, and NaN->0).
                float uf = (xs[k] / z + 0.5f) * 256.0f;
                float vf = (ys[k] / z + 0.5f) * 256.0f;
                int u = (int)fminf(fmaxf(uf, 0.0f), 255.0f);
                int v = (int)fminf(fmaxf(vf, 0.0f), 255.0f);
                atomicAdd(out + v * WW + u, z * d);
            }
        }
    }
}

// Grid-stride masked-MSE partial reduction; wave shuffle reduce then one
// atomic per wave into accum[0]=sum(float), accum[1]=count(int).
__global__ __launch_bounds__(256) void loss_k(
    const float* __restrict__ flat, const float* __restrict__ depth,
    float* __restrict__ accum, int total)
{
    float s = 0.0f;
    int c = 0;
    for (int i = blockIdx.x * blockDim.x + threadIdx.x; i < total;
         i += gridDim.x * blockDim.x) {
        float p = flat[i];
        if (p > 0.0f) {
            float df = p - depth[i];
            s += df * df;
            c++;
        }
    }
    #pragma unroll
    for (int off = 32; off > 0; off >>= 1) {
        s += __shfl_down(s, off);
        c += __shfl_down(c, off);
    }
    if ((threadIdx.x & 63) == 0) {
        atomicAdd(accum, s);
        atomicAdd((int*)accum + 1, c);
    }
}

__global__ void final_k(const float* __restrict__ accum, float* __restrict__ out)
{
    float s = accum[0];
    int c = ((const int*)accum)[1];
    out[0] = s / (float)(c > 1 ? c : 1);
}

extern "C" void kernel_launch(void* const* d_in, const int* in_sizes, int n_in,
                              void* d_out, int out_size, void* d_ws, size_t ws_size,
                              hipStream_t stream) {
    const float* pts   = (const float*)d_in[0];  // (B, N, 3)
    const float* dens  = (const float*)d_in[1];  // (B, N, 1)
    const float* depth = (const float*)d_in[2];  // (B, 1, H, W)
    float* out = (float*)d_out;

    int B = in_sizes[2] / HWSZ;           // 8
    int N = in_sizes[0] / (3 * B);        // 500000

    float* flat  = (float*)d_ws;                  // B*HW floats
    float* accum = flat + (size_t)B * HWSZ;       // [sum(float), count(int)]

    // ws is re-poisoned to 0xAA before every launch: zero it ourselves.
    hipMemsetAsync(d_ws, 0, (size_t)B * HWSZ * sizeof(float) + 2 * sizeof(float),
                   stream);

    int groups = (N + 3) / 4;
    dim3 sgrid((groups + 255) / 256, B);
    scatter_k<<<sgrid, 256, 0, stream>>>(pts, dens, flat, N);

    loss_k<<<dim3(256), 256, 0, stream>>>(flat, depth, accum, B * HWSZ);
    final_k<<<1, 1, 0, stream>>>(accum, out);
}

// Round 2
// 151.289 us; speedup vs baseline: 7.7812x; 7.7812x over previous
//
#include <hip/hip_runtime.h>

#define HH 256
#define WW 256
#define HWSZ (HH * WW)

// Groups of 4 points. Each block handles CHUNK_GROUPS groups (4096 points)
// of one batch: 256 threads x 4 iterations x 4 points.
#define CHUNK_GROUPS 1024
#define NSLOTS 1022  // border pixels: 2*256 (top/bottom rows) + 2*254 (side cols)

// Border pixels (clamped u or v) carry ~91% of accepted points and all the
// atomic contention (corner pixel alone gets ~12.4% of a batch's points).
// Privatize them into a 4KB LDS histogram per block; interior pixels go
// straight to global (spread over 65k addresses, negligible chains).
__global__ __launch_bounds__(256) void scatter_k(
    const float* __restrict__ pts, const float* __restrict__ dens,
    float* __restrict__ flat, int N)
{
    __shared__ float lds[NSLOTS];
    for (int s = threadIdx.x; s < NSLOTS; s += 256) lds[s] = 0.0f;
    __syncthreads();

    int b = blockIdx.y;
    const float* pb = pts + (size_t)b * N * 3;
    const float* db = dens + (size_t)b * N;
    float* out = flat + (size_t)b * HWSZ;

    int ngroups = N >> 2;  // N divisible by 4 (500000)
    int gbase = blockIdx.x * CHUNK_GROUPS;
    const float4* p4 = (const float4*)pb;
    const float4* d4 = (const float4*)db;

    #pragma unroll
    for (int it = 0; it < CHUNK_GROUPS / 256; it++) {
        int g = gbase + it * 256 + threadIdx.x;
        if (g >= ngroups) continue;

        float4 a  = p4[3 * g];
        float4 bb = p4[3 * g + 1];
        float4 c  = p4[3 * g + 2];
        float4 dd = d4[g];

        float xs[4] = {a.x, a.w, bb.z, c.y};
        float ys[4] = {a.y, bb.x, bb.w, c.z};
        float zs[4] = {a.z, bb.y, c.x, c.w};
        float ds[4] = {dd.x, dd.y, dd.z, dd.w};

        #pragma unroll
        for (int k = 0; k < 4; k++) {
            float d = ds[k];
            if (d > 0.5f) {
                float z = zs[k];
                // ref: clip(int32((x/z + 0.5) * 256), 0, 255)
                // trunc-toward-zero then clip == clamp-in-float then trunc
                // (holds for negatives, overflow->inf, and NaN->0).
                float uf = (xs[k] / z + 0.5f) * 256.0f;
                float vf = (ys[k] / z + 0.5f) * 256.0f;
                int u = (int)fminf(fmaxf(uf, 0.0f), 255.0f);
                int v = (int)fminf(fmaxf(vf, 0.0f), 255.0f);
                float val = z * d;
                // Border -> LDS slot; interior -> direct global atomic.
                int slot = -1;
                if (v == 0)            slot = u;
                else if (v == 255)     slot = 256 + u;
                else if (u == 0)       slot = 512 + (v - 1);
                else if (u == 255)     slot = 766 + v;  // 768 + (v-1)
                if (slot >= 0) atomicAdd(&lds[slot], val);
                else           atomicAdd(out + v * WW + u, val);
            }
        }
    }

    __syncthreads();
    // Flush nonzero border slots (adding 0 is a no-op; skipping is exact).
    for (int s = threadIdx.x; s < NSLOTS; s += 256) {
        float v = lds[s];
        if (v != 0.0f) {
            int u, vv;
            if (s < 256)      { vv = 0;        u = s; }
            else if (s < 512) { vv = 255;      u = s - 256; }
            else if (s < 768) { u = 0;         vv = s - 512 + 1; }
            else              { u = 255;       vv = s - 768 + 1; }
            atomicAdd(out + vv * WW + u, v);
        }
    }
}

// Grid-stride masked-MSE partial reduction; wave shuffle reduce then one
// atomic per wave into accum[0]=sum(float), accum[1]=count(int).
__global__ __launch_bounds__(256) void loss_k(
    const float* __restrict__ flat, const float* __restrict__ depth,
    float* __restrict__ accum, int total)
{
    float s = 0.0f;
    int c = 0;
    for (int i = blockIdx.x * blockDim.x + threadIdx.x; i < total;
         i += gridDim.x * blockDim.x) {
        float p = flat[i];
        if (p > 0.0f) {
            float df = p - depth[i];
            s += df * df;
            c++;
        }
    }
    #pragma unroll
    for (int off = 32; off > 0; off >>= 1) {
        s += __shfl_down(s, off);
        c += __shfl_down(c, off);
    }
    if ((threadIdx.x & 63) == 0) {
        atomicAdd(accum, s);
        atomicAdd((int*)accum + 1, c);
    }
}

__global__ void final_k(const float* __restrict__ accum, float* __restrict__ out)
{
    float s = accum[0];
    int c = ((const int*)accum)[1];
    out[0] = s / (float)(c >= 1 ? c : 1);
}

extern "C" void kernel_launch(void* const* d_in, const int* in_sizes, int n_in,
                              void* d_out, int out_size, void* d_ws, size_t ws_size,
                              hipStream_t stream) {
    const float* pts   = (const float*)d_in[0];  // (B, N, 3)
    const float* dens  = (const float*)d_in[1];  // (B, N, 1)
    const float* depth = (const float*)d_in[2];  // (B, 1, H, W)
    float* out = (float*)d_out;

    int B = in_sizes[2] / HWSZ;           // 8
    int N = in_sizes[0] / (3 * B);        // 500000

    float* flat  = (float*)d_ws;                  // B*HW floats
    float* accum = flat + (size_t)B * HWSZ;       // [sum(float), count(int)]

    // ws is re-poisoned to 0xAA before every launch: zero it ourselves.
    hipMemsetAsync(d_ws, 0, (size_t)B * HWSZ * sizeof(float) + 2 * sizeof(float),
                   stream);

    int ngroups = N / 4;
    int cblocks = (ngroups + CHUNK_GROUPS - 1) / CHUNK_GROUPS;  // 123
    dim3 sgrid(cblocks, B);
    scatter_k<<<sgrid, 256, 0, stream>>>(pts, dens, flat, N);

    loss_k<<<dim3(256), 256, 0, stream>>>(flat, depth, accum, B * HWSZ);
    final_k<<<1, 1, 0, stream>>>(accum, out);
}

// Round 3
// 146.457 us; speedup vs baseline: 8.0379x; 1.0330x over previous
//
#include <hip/hip_runtime.h>

#define HH 256
#define WW 256
#define HWSZ (HH * WW)

// Groups of 4 points. Each block handles CHUNK_GROUPS groups (8192 points):
// 256 threads x 8 iterations x 4 points.
#define CHUNK_GROUPS 2048
#define NSLOTS 1022  // border pixels: 2*256 (top/bottom rows) + 2*254 (side cols)

// Contention structure (x/z, y/z are Cauchy): ~35.4% clamp low / 35.4% clamp
// high per axis -> the 4 corner pixels each get ~12.5% of accepted points
// (50% total). Corners are pre-reduced in registers + wave shuffles; the
// remaining border pixels (~41% of accepted, spread over 1018 slots) use a
// 4KB LDS histogram; interior (~8.7%, spread over 65k addresses) goes
// straight to global atomics.
__global__ __launch_bounds__(256) void scatter_k(
    const float* __restrict__ pts, const float* __restrict__ dens,
    float* __restrict__ flat, int N)
{
    __shared__ float lds[NSLOTS];
    for (int s = threadIdx.x; s < NSLOTS; s += 256) lds[s] = 0.0f;
    __syncthreads();

    int b = blockIdx.y;
    const float* pb = pts + (size_t)b * N * 3;
    const float* db = dens + (size_t)b * N;
    float* out = flat + (size_t)b * HWSZ;

    int ngroups = N >> 2;  // N divisible by 4 (500000)
    int gbase = blockIdx.x * CHUNK_GROUPS;
    const float4* p4 = (const float4*)pb;
    const float4* d4 = (const float4*)db;

    // Per-thread register accumulators for the 4 corner pixels.
    // idx = (v==255 ? 2 : 0) | (u==255 ? 1 : 0); LDS slots {0,255,256,511}.
    float corner[4] = {0.0f, 0.0f, 0.0f, 0.0f};

    #pragma unroll
    for (int it = 0; it < CHUNK_GROUPS / 256; it++) {
        int g = gbase + it * 256 + threadIdx.x;
        if (g >= ngroups) continue;

        float4 a  = p4[3 * g];
        float4 bb = p4[3 * g + 1];
        float4 c  = p4[3 * g + 2];
        float4 dd = d4[g];

        float xs[4] = {a.x, a.w, bb.z, c.y};
        float ys[4] = {a.y, bb.x, bb.w, c.z};
        float zs[4] = {a.z, bb.y, c.x, c.w};
        float ds[4] = {dd.x, dd.y, dd.z, dd.w};

        #pragma unroll
        for (int k = 0; k < 4; k++) {
            float d = ds[k];
            if (d > 0.5f) {
                float z = zs[k];
                // ref: clip(int32((x/z + 0.5) * 256), 0, 255)
                // trunc-toward-zero then clip == clamp-in-float then trunc
                // (holds for negatives, overflow->inf, and NaN->0).
                float uf = (xs[k] / z + 0.5f) * 256.0f;
                float vf = (ys[k] / z + 0.5f) * 256.0f;
                int u = (int)fminf(fmaxf(uf, 0.0f), 255.0f);
                int v = (int)fminf(fmaxf(vf, 0.0f), 255.0f);
                float val = z * d;
                bool ub = (u == 0) | (u == 255);
                bool vb = (v == 0) | (v == 255);
                if (ub & vb) {
                    corner[((v == 255) ? 2 : 0) | ((u == 255) ? 1 : 0)] += val;
                } else if (v == 0) {
                    atomicAdd(&lds[u], val);
                } else if (v == 255) {
                    atomicAdd(&lds[256 + u], val);
                } else if (u == 0) {
                    atomicAdd(&lds[512 + (v - 1)], val);
                } else if (u == 255) {
                    atomicAdd(&lds[766 + v], val);  // 768 + (v-1)
                } else {
                    atomicAdd(out + v * WW + u, val);
                }
            }
        }
    }

    // Wave-reduce the 4 corner accumulators; one LDS add per wave per corner.
    #pragma unroll
    for (int j = 0; j < 4; j++) {
        float v = corner[j];
        #pragma unroll
        for (int off = 32; off > 0; off >>= 1) v += __shfl_down(v, off);
        if ((threadIdx.x & 63) == 0) {
            const int cslot[4] = {0, 255, 256, 511};
            atomicAdd(&lds[cslot[j]], v);
        }
    }

    __syncthreads();
    // Flush nonzero border slots (adding 0 is a no-op; skipping is exact).
    for (int s = threadIdx.x; s < NSLOTS; s += 256) {
        float v = lds[s];
        if (v != 0.0f) {
            int u, vv;
            if (s < 256)      { vv = 0;        u = s; }
            else if (s < 512) { vv = 255;      u = s - 256; }
            else if (s < 768) { u = 0;         vv = s - 512 + 1; }
            else              { u = 255;       vv = s - 768 + 1; }
            atomicAdd(out + vv * WW + u, v);
        }
    }
}

// Fused masked-MSE reduction + finalize. float4 grid-stride; wave shuffle
// reduce; one atomic per wave into accum[0]=sum(float), accum[1]=count(int).
// Last finishing block (device-scope done counter) computes out[0].
__global__ __launch_bounds__(256) void loss_k(
    const float* __restrict__ flat, const float* __restrict__ depth,
    float* __restrict__ accum, int* __restrict__ done,
    float* __restrict__ out, int total4, int nblocks)
{
    const float4* f4 = (const float4*)flat;
    const float4* z4 = (const float4*)depth;
    float s = 0.0f;
    int c = 0;
    for (int i = blockIdx.x * blockDim.x + threadIdx.x; i < total4;
         i += gridDim.x * blockDim.x) {
        float4 p = f4[i];
        float4 q = z4[i];
        if (p.x > 0.0f) { float df = p.x - q.x; s += df * df; c++; }
        if (p.y > 0.0f) { float df = p.y - q.y; s += df * df; c++; }
        if (p.z > 0.0f) { float df = p.z - q.z; s += df * df; c++; }
        if (p.w > 0.0f) { float df = p.w - q.w; s += df * df; c++; }
    }
    #pragma unroll
    for (int off = 32; off > 0; off >>= 1) {
        s += __shfl_down(s, off);
        c += __shfl_down(c, off);
    }
    if ((threadIdx.x & 63) == 0) {
        atomicAdd(accum, s);
        atomicAdd((int*)accum + 1, c);
    }
    __syncthreads();
    if (threadIdx.x == 0) {
        __threadfence();
        int old = atomicAdd(done, 1);
        if (old == nblocks - 1) {
            // L2-coherent reads of the final totals.
            float ts = atomicAdd(accum, 0.0f);
            int tc = atomicAdd((int*)accum + 1, 0);
            out[0] = ts / (float)(tc >= 1 ? tc : 1);
        }
    }
}

extern "C" void kernel_launch(void* const* d_in, const int* in_sizes, int n_in,
                              void* d_out, int out_size, void* d_ws, size_t ws_size,
                              hipStream_t stream) {
    const float* pts   = (const float*)d_in[0];  // (B, N, 3)
    const float* dens  = (const float*)d_in[1];  // (B, N, 1)
    const float* depth = (const float*)d_in[2];  // (B, 1, H, W)
    float* out = (float*)d_out;

    int B = in_sizes[2] / HWSZ;           // 8
    int N = in_sizes[0] / (3 * B);        // 500000

    float* flat  = (float*)d_ws;                  // B*HW floats
    float* accum = flat + (size_t)B * HWSZ;       // [sum(float), count(int)]
    int*   done  = (int*)(accum + 2);

    // ws is re-poisoned to 0xAA before every launch: zero flat+accum+done.
    hipMemsetAsync(d_ws, 0, ((size_t)B * HWSZ + 4) * sizeof(float), stream);

    int ngroups = N / 4;
    int cblocks = (ngroups + CHUNK_GROUPS - 1) / CHUNK_GROUPS;  // 62
    dim3 sgrid(cblocks, B);
    scatter_k<<<sgrid, 256, 0, stream>>>(pts, dens, flat, N);

    int total4 = B * HWSZ / 4;
    int lblocks = 128;
    loss_k<<<dim3(lblocks), 256, 0, stream>>>(flat, depth, accum, done, out,
                                              total4, lblocks);
}